// Round 5
// baseline (14282.770 us; speedup 1.0000x reference)
//
#include <hip/hip_runtime.h>

// BiLSTM tagger, MI355X. Round 5: k_recurrent split 8->32 WGs/direction.
//  THEORY (r4 post-mortem): compiler refuses to keep >~128 live VGPRs regardless of
//  __restrict__/__launch_bounds__ — 128-float weight arrays get re-streamed from L2
//  (~2340 cy/step, matches measured ~2950 cy/step). Fix: 32 WGs/dir, 32 rows/WG,
//  8 float4 weights/thread (32 VGPRs) — under the pressure threshold, LICM hoists.
//  Row assignment is unit-major within waves: all 4 gates of a unit live in one wave
//  -> activation path is within-wave (shfl only), ONE barrier/step (after wave-0 poll).
//  Exchange: unchanged tagged u64 parity protocol, now 32 producers x 8 units each.
//
// Workspace (d_ws) ~92.5 MB:
//   [0)          preC      256 KB
//   [262144)     whhTc     256 KB
//   [524288)     embeds    12 MB   [8192][384]
//   [13107200)   pregates  64 MB   [2][8192][1024] (gate-major n)
//   [80216064)   hout      16 MB   [8192][512]  ([hf|hb])
//   [96993280)   hbuf      8 KB    [2][2][256] u64 tagged h (tag=step+1, poison-safe)

#define S_LEN 8192
#define LC    16
#define DW    256
#define DC    64
#define HC    128
#define H2    256
#define NG    1024   // 4*H2
#define NTAG  64
#define CV    128

__device__ __forceinline__ float sigmoid_f(float x){
  return __frcp_rn(1.0f + __expf(-x));
}
__device__ __forceinline__ float tanh_f(float x){
  float a = fabsf(x);
  float t = 1.0f - 2.0f * __frcp_rn(__expf(2.0f*a) + 1.0f);
  return copysignf(t, x);
}

// ---------------------------------------------------------------- k_prep
__global__ __launch_bounds__(512) void k_prep(
    const float* __restrict__ char_emb, const float* __restrict__ char_Wih,
    const float* __restrict__ char_Whh, const float* __restrict__ char_b,
    float* __restrict__ preC, float* __restrict__ whhTc)
{
  int blk = blockIdx.x, tid = threadIdx.x;
  __shared__ float esh[DC];
  if (blk < CV){
    if (tid < DC) esh[tid] = char_emb[blk*DC + tid];
    __syncthreads();
    const float* wr = char_Wih + (size_t)tid*DC;
    float acc = char_b[tid];
#pragma unroll
    for (int d=0; d<DC; d+=4){
      float4 wv = *(const float4*)&wr[d];
      acc += wv.x*esh[d] + wv.y*esh[d+1] + wv.z*esh[d+2] + wv.w*esh[d+3];
    }
    preC[(size_t)blk*512 + tid] = acc;
  } else {
    int k = blk - CV;
    whhTc[(size_t)k*512 + tid] = char_Whh[(size_t)tid*HC + k];
  }
}

// ---------------------------------------------------------------- k_char_lstm
__global__ __launch_bounds__(256) void k_char_lstm(
    const int* __restrict__ charsets, const int* __restrict__ lengths,
    const float* __restrict__ preC, const float* __restrict__ whhTc,
    float* __restrict__ embeds)
{
  int blk = blockIdx.x, tid = threadIdx.x;
  int s0 = blk*16;
  __shared__ float h_sh[16][132];
  __shared__ float gsh[512][17];
  __shared__ int   ch_sh[16];

  for (int i = tid; i < 16*132; i += 256) (&h_sh[0][0])[i] = 0.0f;

  int uw  = tid & 15;
  int ujg = tid >> 4;
  float c[8];
#pragma unroll
  for (int u=0; u<8; u++) c[u] = 0.0f;
  int lw = lengths[s0 + uw];

  int g0 = tid, g1 = tid + 256;
  __syncthreads();

  for (int t=0; t<LC; t++){
    if (tid < 16) ch_sh[tid] = charsets[(size_t)(s0+tid)*LC + t];
    __syncthreads();                                        // (A)

    float acc0[16], acc1[16];
#pragma unroll
    for (int w=0; w<16; w++){
      int ch = ch_sh[w];
      acc0[w] = preC[(size_t)ch*512 + g0];
      acc1[w] = preC[(size_t)ch*512 + g1];
    }
    for (int k4=0; k4<HC; k4+=4){
      float w00 = whhTc[(size_t)(k4+0)*512 + g0];
      float w01 = whhTc[(size_t)(k4+1)*512 + g0];
      float w02 = whhTc[(size_t)(k4+2)*512 + g0];
      float w03 = whhTc[(size_t)(k4+3)*512 + g0];
      float w10 = whhTc[(size_t)(k4+0)*512 + g1];
      float w11 = whhTc[(size_t)(k4+1)*512 + g1];
      float w12 = whhTc[(size_t)(k4+2)*512 + g1];
      float w13 = whhTc[(size_t)(k4+3)*512 + g1];
#pragma unroll
      for (int w=0; w<16; w++){
        float4 h4 = *(const float4*)&h_sh[w][k4];
        acc0[w] += w00*h4.x + w01*h4.y + w02*h4.z + w03*h4.w;
        acc1[w] += w10*h4.x + w11*h4.y + w12*h4.z + w13*h4.w;
      }
    }
#pragma unroll
    for (int w=0; w<16; w++){ gsh[g0][w] = acc0[w]; gsh[g1][w] = acc1[w]; }
    __syncthreads();                                        // (G)

    float hnew[8];
#pragma unroll
    for (int u=0; u<8; u++){
      int j = ujg*8 + u;
      float gi = sigmoid_f(gsh[j][uw]);
      float gf = sigmoid_f(gsh[HC + j][uw]);
      float gg = tanh_f   (gsh[2*HC + j][uw]);
      float go = sigmoid_f(gsh[3*HC + j][uw]);
      c[u] = gf*c[u] + gi*gg;
      hnew[u] = go * tanh_f(c[u]);
    }
#pragma unroll
    for (int u=0; u<8; u+=4)
      *(float4*)&h_sh[uw][ujg*8 + u] = make_float4(hnew[u],hnew[u+1],hnew[u+2],hnew[u+3]);
    if (t == lw-1){
#pragma unroll
      for (int u=0; u<8; u+=4)
        *(float4*)&embeds[(size_t)(s0+uw)*384 + ujg*8 + u]
            = make_float4(hnew[u],hnew[u+1],hnew[u+2],hnew[u+3]);
    }
  }
}

// ---------------------------------------------------------------- k_gather
__global__ __launch_bounds__(256) void k_gather(
    const int* __restrict__ sentence, const float* __restrict__ word_emb,
    float* __restrict__ embeds)
{
  int blk = blockIdx.x, tid = threadIdx.x;
  int s = blk*8 + (tid >> 5);
  int lane = tid & 31;
  int idx = sentence[s];
  const float4* src = (const float4*)(word_emb + (size_t)idx*DW);
  float4* dst = (float4*)(embeds + (size_t)s*384 + 128);
  dst[lane]      = src[lane];
  dst[lane + 32] = src[lane + 32];
}

// ---------------------------------------------------------------- k_pregate
// Output layout: pregates[dir][t][n], n gate-major (i,f,g,o blocks of 256)
__global__ __launch_bounds__(256) void k_pregate(
    const float* __restrict__ embeds,
    const float* __restrict__ Wih_fw, const float* __restrict__ b_fw,
    const float* __restrict__ Wih_bw, const float* __restrict__ b_bw,
    float* __restrict__ pregates)
{
  int dir = blockIdx.z;
  const float* W    = dir ? Wih_bw : Wih_fw;
  const float* bias = dir ? b_bw   : b_fw;
  int t0 = blockIdx.x*64, n0 = blockIdx.y*64;
  __shared__ float a_sh[16][68];
  __shared__ float b_sh[16][68];
  int tid = threadIdx.x;
  int li = tid & 63, kq = tid >> 6;
  int ti = tid >> 4, tj = tid & 15;
  float acc[4][4];
#pragma unroll
  for (int ii=0; ii<4; ii++)
#pragma unroll
    for (int jj=0; jj<4; jj++) acc[ii][jj] = 0.0f;

  for (int k0=0; k0<384; k0+=16){
    float4 av = *(const float4*)&embeds[(size_t)(t0+li)*384 + k0 + kq*4];
    float4 bv = *(const float4*)&W     [(size_t)(n0+li)*384 + k0 + kq*4];
    __syncthreads();
    a_sh[kq*4+0][li]=av.x; a_sh[kq*4+1][li]=av.y; a_sh[kq*4+2][li]=av.z; a_sh[kq*4+3][li]=av.w;
    b_sh[kq*4+0][li]=bv.x; b_sh[kq*4+1][li]=bv.y; b_sh[kq*4+2][li]=bv.z; b_sh[kq*4+3][li]=bv.w;
    __syncthreads();
#pragma unroll
    for (int kk=0; kk<16; kk++){
      float4 a4 = *(const float4*)&a_sh[kk][ti*4];
      float4 b4 = *(const float4*)&b_sh[kk][tj*4];
      float aa[4] = {a4.x,a4.y,a4.z,a4.w};
      float bb[4] = {b4.x,b4.y,b4.z,b4.w};
#pragma unroll
      for (int ii=0; ii<4; ii++)
#pragma unroll
        for (int jj=0; jj<4; jj++) acc[ii][jj] += aa[ii]*bb[jj];
    }
  }
  float4 bias4 = *(const float4*)&bias[n0 + tj*4];
  float bb2[4] = {bias4.x,bias4.y,bias4.z,bias4.w};
#pragma unroll
  for (int ii=0; ii<4; ii++){
    float4 o = make_float4(acc[ii][0]+bb2[0], acc[ii][1]+bb2[1],
                           acc[ii][2]+bb2[2], acc[ii][3]+bb2[3]);
    *(float4*)&pregates[((size_t)dir*S_LEN + (t0+ti*4+ii))*NG + n0 + tj*4] = o;
  }
}

// ---------------------------------------------------------------- k_recurrent
// 64 blocks: dir = b>>5, wgi = b&31. WG owns units [wgi*8, wgi*8+8).
// Wave w owns units wgi*8 + 2w, +2w+1 (all 4 gates of each -> activation is within-wave).
// Lane l: rloc=l>>3 (row-in-wave, unit-major: uloc=rloc>>2, gate q=rloc&3), ke=l&7.
// Thread weights: Whh[row][ke*32..+32] = 8 float4 (32 VGPRs -> hoistable).
// Wave 0 polls the tagged exchange, fills h_sh; ONE __syncthreads per step.
__global__ __launch_bounds__(256, 1) void k_recurrent(
    const float* __restrict__ Whh_fw, const float* __restrict__ Whh_bw,
    const float* __restrict__ pregates,
    unsigned long long* __restrict__ hbuf,
    float* __restrict__ hout)
{
  int b = blockIdx.x;            // 0..63
  int dir = b >> 5, wgi = b & 31;
  int tid = threadIdx.x;
  int wave = tid >> 6, l = tid & 63;
  int rloc = l >> 3;             // 0..7
  int ke   = l & 7;
  int uloc = rloc >> 2;          // 0..1
  int q    = rloc & 3;           // gate i,f,g,o
  int u    = wgi*8 + wave*2 + uloc;   // global unit 0..255
  int row  = q*H2 + u;                // gate row 0..1023

  const float* Whh = dir ? Whh_bw : Whh_fw;
  const float* pgb = pregates + (size_t)dir * S_LEN * NG;
  unsigned long long* __restrict__ hb = hbuf + (size_t)dir * 2 * H2;

  __shared__ float h_sh[8*36];   // padded: ph(k)=(k>>5)*36+(k&31)

  // per-thread weights: one gate row x 32-k slice
  float4 w4[8];
  {
    const float4* wr = (const float4*)(Whh + (size_t)row*H2 + ke*32);
#pragma unroll
    for (int i=0; i<8; i++) w4[i] = wr[i];
  }

  h_sh[(tid>>5)*36 + (tid&31)] = 0.0f;   // h_{-1}=0 (tid covers 0..255)
  float c = 0.0f;
  __syncthreads();

  float pgv;
  {
    int t0 = dir ? (S_LEN-1) : 0;
    pgv = pgb[(size_t)t0*NG + row];
  }

  for (int s=0; s<S_LEN; s++){
    int t = dir ? (S_LEN-1-s) : s;

    // matvec: a = dot(Whh[row][ke*32..+32], h[ke*32..+32])
    const float* hk = &h_sh[ke*36];
    float a = 0.0f;
#pragma unroll
    for (int i=0; i<8; i++){
      float4 h4 = *(const float4*)&hk[i*4];
      a += w4[i].x*h4.x + w4[i].y*h4.y + w4[i].z*h4.z + w4[i].w*h4.w;
    }
    // butterfly over ke: all 8 lanes of the group get the full row sum
    a += __shfl_xor(a, 1);
    a += __shfl_xor(a, 2);
    a += __shfl_xor(a, 4);
    a += pgv;

    // per-lane activation (gate g uses tanh = 2*sigmoid(2x)-1)
    float xx  = (q==2) ? (a + a) : a;
    float sg  = sigmoid_f(xx);
    float act = (q==2) ? (sg + sg - 1.0f) : sg;

    // gather the 4 gates of this lane's unit (all within-wave)
    int base = uloc*32 + ke;
    float iA = __shfl(act, base);
    float fA = __shfl(act, base + 8);
    float gA = __shfl(act, base + 16);
    float oA = __shfl(act, base + 24);
    c = fA*c + iA*gA;
    float hn = oA * tanh_f(c);

    if ((l & 31) == 0){          // one lane per unit: tagged store + hout
      unsigned long long pack =
          ((unsigned long long)__float_as_uint(hn) << 32) | (unsigned long long)(unsigned)(s+1);
      __hip_atomic_store(&hb[(s&1)*H2 + u], pack,
                         __ATOMIC_RELAXED, __HIP_MEMORY_SCOPE_AGENT);
      hout[(size_t)t*512 + dir*H2 + u] = hn;
    }

    if (s+1 < S_LEN){
      int tn = dir ? (S_LEN-2-s) : (s+1);
      pgv = pgb[(size_t)tn*NG + row];          // prefetch next pregate

      if (wave == 0){                          // wave 0: poll all 256 tagged slots
        unsigned tag = (unsigned)(s+1);
        unsigned long long* __restrict__ base2 = &hb[(s&1)*H2];
        unsigned long long v0,v1,v2,v3;
        for (;;){
          v0 = __hip_atomic_load(base2+l,     __ATOMIC_RELAXED, __HIP_MEMORY_SCOPE_AGENT);
          v1 = __hip_atomic_load(base2+l+64,  __ATOMIC_RELAXED, __HIP_MEMORY_SCOPE_AGENT);
          v2 = __hip_atomic_load(base2+l+128, __ATOMIC_RELAXED, __HIP_MEMORY_SCOPE_AGENT);
          v3 = __hip_atomic_load(base2+l+192, __ATOMIC_RELAXED, __HIP_MEMORY_SCOPE_AGENT);
          if ( ((unsigned)v0==tag) & ((unsigned)v1==tag) &
               ((unsigned)v2==tag) & ((unsigned)v3==tag) ) break;
        }
        h_sh[((l    )>>5)*36 + ((l    )&31)] = __uint_as_float((unsigned)(v0>>32));
        h_sh[((l+ 64)>>5)*36 + ((l+ 64)&31)] = __uint_as_float((unsigned)(v1>>32));
        h_sh[((l+128)>>5)*36 + ((l+128)&31)] = __uint_as_float((unsigned)(v2>>32));
        h_sh[((l+192)>>5)*36 + ((l+192)&31)] = __uint_as_float((unsigned)(v3>>32));
      }
      __syncthreads();           // single barrier per step
    }
  }
}

// ---------------------------------------------------------------- k_output
__global__ __launch_bounds__(256) void k_output(
    const float* __restrict__ hout, const float* __restrict__ outW,
    const float* __restrict__ outb, float* __restrict__ out)
{
  __shared__ float wT[128][66];
  __shared__ float hsh[32][132];
  __shared__ float lsh[32][66];
  __shared__ float msh[32][2];
  int t0 = blockIdx.x*32, tid = threadIdx.x;
  int n  = tid & 63, tg = tid >> 6;
  int sl = tid >> 3, kg = tid & 7;
  int wn = tid & 63, wk = tid >> 6;
  float acc[8];
#pragma unroll
  for (int u=0; u<8; u++) acc[u] = 0.0f;

  for (int kc=0; kc<4; kc++){
    int k0 = kc*128;
    float4 wreg[8];
#pragma unroll
    for (int e=0; e<8; e++) wreg[e] = *(const float4*)&outW[(size_t)wn*512 + k0 + wk*32 + e*4];
    float4 hreg[4];
#pragma unroll
    for (int e=0; e<4; e++) hreg[e] = *(const float4*)&hout[(size_t)(t0+sl)*512 + k0 + kg*16 + e*4];
    __syncthreads();
#pragma unroll
    for (int e=0; e<8; e++){
      int kk = wk*32 + e*4;
      wT[kk+0][wn]=wreg[e].x; wT[kk+1][wn]=wreg[e].y; wT[kk+2][wn]=wreg[e].z; wT[kk+3][wn]=wreg[e].w;
    }
#pragma unroll
    for (int e=0; e<4; e++) *(float4*)&hsh[sl][kg*16 + e*4] = hreg[e];
    __syncthreads();
#pragma unroll
    for (int kk4=0; kk4<128; kk4+=4){
      float w0 = wT[kk4+0][n], w1 = wT[kk4+1][n], w2 = wT[kk4+2][n], w3 = wT[kk4+3][n];
#pragma unroll
      for (int u=0; u<8; u++){
        float4 h4 = *(const float4*)&hsh[tg*8+u][kk4];
        acc[u] += w0*h4.x + w1*h4.y + w2*h4.z + w3*h4.w;
      }
    }
  }
  float bn = outb[n];
#pragma unroll
  for (int u=0; u<8; u++) lsh[tg*8+u][n] = acc[u] + bn;
  __syncthreads();
  if (tid < 32){
    float M = -3.4e38f;
    for (int j=0; j<NTAG; j++) M = fmaxf(M, lsh[tid][j]);
    float ssum = 0.0f;
    for (int j=0; j<NTAG; j++) ssum += expf(lsh[tid][j] - M);
    msh[tid][0] = M; msh[tid][1] = logf(ssum);
  }
  __syncthreads();
#pragma unroll
  for (int u=0; u<8; u++){
    int tt = tg*8+u;
    out[(size_t)(t0+tt)*NTAG + n] = lsh[tt][n] - msh[tt][0] - msh[tt][1];
  }
}

// ---------------------------------------------------------------- launch
extern "C" void kernel_launch(void* const* d_in, const int* in_sizes, int n_in,
                              void* d_out, int out_size, void* d_ws, size_t ws_size,
                              hipStream_t stream)
{
  (void)in_sizes; (void)n_in; (void)out_size; (void)ws_size;
  const int*   sentence = (const int*)d_in[0];
  const int*   charsets = (const int*)d_in[1];
  const int*   char_len = (const int*)d_in[2];
  const float* word_emb = (const float*)d_in[3];
  const float* char_emb = (const float*)d_in[4];
  const float* char_Wih = (const float*)d_in[5];
  const float* char_Whh = (const float*)d_in[6];
  const float* char_b   = (const float*)d_in[7];
  const float* fw_Wih   = (const float*)d_in[8];
  const float* fw_Whh   = (const float*)d_in[9];
  const float* fw_b     = (const float*)d_in[10];
  const float* bw_Wih   = (const float*)d_in[11];
  const float* bw_Whh   = (const float*)d_in[12];
  const float* bw_b     = (const float*)d_in[13];
  const float* out_W    = (const float*)d_in[14];
  const float* out_b    = (const float*)d_in[15];
  float* out = (float*)d_out;

  char* ws = (char*)d_ws;
  float* preC     = (float*)(ws);
  float* whhTc    = (float*)(ws + 262144);
  float* embeds   = (float*)(ws + 524288);
  float* pregates = (float*)(ws + 13107200);
  float* houtb    = (float*)(ws + 80216064);
  unsigned long long* hbuf = (unsigned long long*)(ws + 96993280);

  k_prep     <<<256,  512, 0, stream>>>(char_emb, char_Wih, char_Whh, char_b, preC, whhTc);
  k_char_lstm<<<512,  256, 0, stream>>>(charsets, char_len, preC, whhTc, embeds);
  k_gather   <<<1024, 256, 0, stream>>>(sentence, word_emb, embeds);
  k_pregate  <<<dim3(128,16,2), 256, 0, stream>>>(embeds, fw_Wih, fw_b, bw_Wih, bw_b, pregates);
  k_recurrent<<<64,   256, 0, stream>>>(fw_Whh, bw_Whh, pregates, hbuf, houtb);
  k_output   <<<256,  256, 0, stream>>>(houtb, out_W, out_b, out);
}

// Round 6
// 13895.360 us; speedup vs baseline: 1.0279x; 1.0279x over previous
//
#include <hip/hip_runtime.h>

// BiLSTM tagger, MI355X. Round 6: k_recurrent with WEIGHTS IN LDS (fp16) + clean streams.
//  r5 post-mortem: AMDGPU RA remats loads from noclobber const globals into the loop
//  (VGPR=36 — even 32 floats refused residency). LDS sidesteps the RA entirely.
//  - 32 WG/dir; WG stages its 32x256 Whh slice to LDS as fp16 (16 KB), chunk-interleaved
//    [wave][j][ke][rloc] so per-step reads are lane-contiguous ds_read_b128 (~12cy floor).
//  - h kept in LDS as fp16, pad-40 layout: chunk = 5*ke+j -> distinct mod 8, rloc broadcast.
//  - dot: v_dot2_f32_f16 (fp32 accumulator); activations within-wave via shfl; one barrier.
//  - poll distributed: wave w polls slots [64w,64w+64) (1 coalesced u64/lane), converts to
//    fp16, writes h16. Tagged-parity protocol unchanged (tag=s+1, poison-safe).
//  - pregates re-laid out [dir][t][wg][32]: one contiguous 128B read/WG/step, prefetched
//    before the poll (r5's scattered per-thread reads caused the 336MB FETCH).
//
// Workspace (d_ws) ~92.5 MB:
//   [0)          preC      256 KB
//   [262144)     whhTc     256 KB
//   [524288)     embeds    12 MB   [8192][384]
//   [13107200)   pregates  64 MB   [2][8192][32wg][32]
//   [80216064)   hout      16 MB   [8192][512]  ([hf|hb])
//   [96993280)   hbuf      8 KB    [2][2][256] u64 tagged h

#define S_LEN 8192
#define LC    16
#define DW    256
#define DC    64
#define HC    128
#define H2    256
#define NG    1024   // 4*H2
#define NTAG  64
#define CV    128

typedef _Float16 f16x2 __attribute__((ext_vector_type(2)));
union F4H { float4 f4; f16x2 h2[4]; };

__device__ __forceinline__ float dot2f(f16x2 a, f16x2 b, float c){
#if __has_builtin(__builtin_amdgcn_fdot2)
  return __builtin_amdgcn_fdot2(a, b, c, false);
#else
  return c + (float)a[0]*(float)b[0] + (float)a[1]*(float)b[1];
#endif
}

__device__ __forceinline__ float sigmoid_f(float x){
  return __frcp_rn(1.0f + __expf(-x));
}
__device__ __forceinline__ float tanh_f(float x){
  float a = fabsf(x);
  float t = 1.0f - 2.0f * __frcp_rn(__expf(2.0f*a) + 1.0f);
  return copysignf(t, x);
}

// ---------------------------------------------------------------- k_prep
__global__ __launch_bounds__(512) void k_prep(
    const float* __restrict__ char_emb, const float* __restrict__ char_Wih,
    const float* __restrict__ char_Whh, const float* __restrict__ char_b,
    float* __restrict__ preC, float* __restrict__ whhTc)
{
  int blk = blockIdx.x, tid = threadIdx.x;
  __shared__ float esh[DC];
  if (blk < CV){
    if (tid < DC) esh[tid] = char_emb[blk*DC + tid];
    __syncthreads();
    const float* wr = char_Wih + (size_t)tid*DC;
    float acc = char_b[tid];
#pragma unroll
    for (int d=0; d<DC; d+=4){
      float4 wv = *(const float4*)&wr[d];
      acc += wv.x*esh[d] + wv.y*esh[d+1] + wv.z*esh[d+2] + wv.w*esh[d+3];
    }
    preC[(size_t)blk*512 + tid] = acc;
  } else {
    int k = blk - CV;
    whhTc[(size_t)k*512 + tid] = char_Whh[(size_t)tid*HC + k];
  }
}

// ---------------------------------------------------------------- k_char_lstm
__global__ __launch_bounds__(256) void k_char_lstm(
    const int* __restrict__ charsets, const int* __restrict__ lengths,
    const float* __restrict__ preC, const float* __restrict__ whhTc,
    float* __restrict__ embeds)
{
  int blk = blockIdx.x, tid = threadIdx.x;
  int s0 = blk*16;
  __shared__ float h_sh[16][132];
  __shared__ float gsh[512][17];
  __shared__ int   ch_sh[16];

  for (int i = tid; i < 16*132; i += 256) (&h_sh[0][0])[i] = 0.0f;

  int uw  = tid & 15;
  int ujg = tid >> 4;
  float c[8];
#pragma unroll
  for (int u=0; u<8; u++) c[u] = 0.0f;
  int lw = lengths[s0 + uw];

  int g0 = tid, g1 = tid + 256;
  __syncthreads();

  for (int t=0; t<LC; t++){
    if (tid < 16) ch_sh[tid] = charsets[(size_t)(s0+tid)*LC + t];
    __syncthreads();                                        // (A)

    float acc0[16], acc1[16];
#pragma unroll
    for (int w=0; w<16; w++){
      int ch = ch_sh[w];
      acc0[w] = preC[(size_t)ch*512 + g0];
      acc1[w] = preC[(size_t)ch*512 + g1];
    }
    for (int k4=0; k4<HC; k4+=4){
      float w00 = whhTc[(size_t)(k4+0)*512 + g0];
      float w01 = whhTc[(size_t)(k4+1)*512 + g0];
      float w02 = whhTc[(size_t)(k4+2)*512 + g0];
      float w03 = whhTc[(size_t)(k4+3)*512 + g0];
      float w10 = whhTc[(size_t)(k4+0)*512 + g1];
      float w11 = whhTc[(size_t)(k4+1)*512 + g1];
      float w12 = whhTc[(size_t)(k4+2)*512 + g1];
      float w13 = whhTc[(size_t)(k4+3)*512 + g1];
#pragma unroll
      for (int w=0; w<16; w++){
        float4 h4 = *(const float4*)&h_sh[w][k4];
        acc0[w] += w00*h4.x + w01*h4.y + w02*h4.z + w03*h4.w;
        acc1[w] += w10*h4.x + w11*h4.y + w12*h4.z + w13*h4.w;
      }
    }
#pragma unroll
    for (int w=0; w<16; w++){ gsh[g0][w] = acc0[w]; gsh[g1][w] = acc1[w]; }
    __syncthreads();                                        // (G)

    float hnew[8];
#pragma unroll
    for (int u=0; u<8; u++){
      int j = ujg*8 + u;
      float gi = sigmoid_f(gsh[j][uw]);
      float gf = sigmoid_f(gsh[HC + j][uw]);
      float gg = tanh_f   (gsh[2*HC + j][uw]);
      float go = sigmoid_f(gsh[3*HC + j][uw]);
      c[u] = gf*c[u] + gi*gg;
      hnew[u] = go * tanh_f(c[u]);
    }
#pragma unroll
    for (int u=0; u<8; u+=4)
      *(float4*)&h_sh[uw][ujg*8 + u] = make_float4(hnew[u],hnew[u+1],hnew[u+2],hnew[u+3]);
    if (t == lw-1){
#pragma unroll
      for (int u=0; u<8; u+=4)
        *(float4*)&embeds[(size_t)(s0+uw)*384 + ujg*8 + u]
            = make_float4(hnew[u],hnew[u+1],hnew[u+2],hnew[u+3]);
    }
  }
}

// ---------------------------------------------------------------- k_gather
__global__ __launch_bounds__(256) void k_gather(
    const int* __restrict__ sentence, const float* __restrict__ word_emb,
    float* __restrict__ embeds)
{
  int blk = blockIdx.x, tid = threadIdx.x;
  int s = blk*8 + (tid >> 5);
  int lane = tid & 31;
  int idx = sentence[s];
  const float4* src = (const float4*)(word_emb + (size_t)idx*DW);
  float4* dst = (float4*)(embeds + (size_t)s*384 + 128);
  dst[lane]      = src[lane];
  dst[lane + 32] = src[lane + 32];
}

// ---------------------------------------------------------------- k_pregate
// Output layout: pregates[dir][t][wg=u>>3][q*8 + (u&7)]  (gate rows n = q*256+u)
__global__ __launch_bounds__(256) void k_pregate(
    const float* __restrict__ embeds,
    const float* __restrict__ Wih_fw, const float* __restrict__ b_fw,
    const float* __restrict__ Wih_bw, const float* __restrict__ b_bw,
    float* __restrict__ pregates)
{
  int dir = blockIdx.z;
  const float* W    = dir ? Wih_bw : Wih_fw;
  const float* bias = dir ? b_bw   : b_fw;
  int t0 = blockIdx.x*64, n0 = blockIdx.y*64;
  __shared__ float a_sh[16][68];
  __shared__ float b_sh[16][68];
  int tid = threadIdx.x;
  int li = tid & 63, kq = tid >> 6;
  int ti = tid >> 4, tj = tid & 15;
  float acc[4][4];
#pragma unroll
  for (int ii=0; ii<4; ii++)
#pragma unroll
    for (int jj=0; jj<4; jj++) acc[ii][jj] = 0.0f;

  for (int k0=0; k0<384; k0+=16){
    float4 av = *(const float4*)&embeds[(size_t)(t0+li)*384 + k0 + kq*4];
    float4 bv = *(const float4*)&W     [(size_t)(n0+li)*384 + k0 + kq*4];
    __syncthreads();
    a_sh[kq*4+0][li]=av.x; a_sh[kq*4+1][li]=av.y; a_sh[kq*4+2][li]=av.z; a_sh[kq*4+3][li]=av.w;
    b_sh[kq*4+0][li]=bv.x; b_sh[kq*4+1][li]=bv.y; b_sh[kq*4+2][li]=bv.z; b_sh[kq*4+3][li]=bv.w;
    __syncthreads();
#pragma unroll
    for (int kk=0; kk<16; kk++){
      float4 a4 = *(const float4*)&a_sh[kk][ti*4];
      float4 b4 = *(const float4*)&b_sh[kk][tj*4];
      float aa[4] = {a4.x,a4.y,a4.z,a4.w};
      float bb[4] = {b4.x,b4.y,b4.z,b4.w};
#pragma unroll
      for (int ii=0; ii<4; ii++)
#pragma unroll
        for (int jj=0; jj<4; jj++) acc[ii][jj] += aa[ii]*bb[jj];
    }
  }
  float4 bias4 = *(const float4*)&bias[n0 + tj*4];
  float bb2[4] = {bias4.x,bias4.y,bias4.z,bias4.w};
  int q = n0 >> 8;                        // gate block, constant per tile
#pragma unroll
  for (int ii=0; ii<4; ii++){
    size_t base = ((size_t)dir*S_LEN + (t0+ti*4+ii))*NG;
#pragma unroll
    for (int jj=0; jj<4; jj++){
      int u = (n0 & 255) + tj*4 + jj;
      pregates[base + (size_t)(u>>3)*32 + q*8 + (u&7)] = acc[ii][jj] + bb2[jj];
    }
  }
}

// ---------------------------------------------------------------- k_recurrent
// 64 blocks: dir=b>>5, wgi=b&31; WG owns units [wgi*8, wgi*8+8).
// Thread (wave, rloc=l>>3, ke=l&7): gate q=rloc&3 of unit u=wgi*8+wave*2+(rloc>>2),
// k-slice [32ke,32ke+32). Weights fp16 in LDS, chunk-interleaved [wave][j][ke][rloc]
// (per-instr lane-contiguous b128). h fp16 in LDS pad-40. One barrier/step.
__global__ __launch_bounds__(256) void k_recurrent(
    const float* __restrict__ Whh_fw, const float* __restrict__ Whh_bw,
    const float* __restrict__ pg2,
    unsigned long long* __restrict__ hbuf,
    float* __restrict__ hout)
{
  int b = blockIdx.x;            // 0..63
  int dir = b >> 5, wgi = b & 31;
  int tid = threadIdx.x;
  int wave = tid >> 6, l = tid & 63;
  int rloc = l >> 3, ke = l & 7;
  int uloc = rloc >> 2, q = rloc & 3;
  int u   = wgi*8 + wave*2 + uloc;     // global unit 0..255
  int row = q*H2 + u;                  // gate row (PyTorch i,f,g,o blocks)

  const float* Whh = dir ? Whh_bw : Whh_fw;
  const float* pgb = pg2 + (size_t)dir * S_LEN * NG;   // [t][32wg][32]
  unsigned long long* __restrict__ hb = hbuf + (size_t)dir * 2 * H2;

  __shared__ float4    wlds4[4][4][8][8];   // [wave][j][ke][rloc]: 8 fp16 weights/chunk
  __shared__ __align__(16) _Float16 h16[8*40];  // ph(k)=(k>>5)*40+(k&31)

  // ---- stage weights: Whh[row][ke*32+8j .. +8] -> wlds4[wave][j][ke][rloc]
  {
    const float* wr = Whh + (size_t)row*H2 + ke*32;
#pragma unroll
    for (int j=0; j<4; j++){
      float4 v0 = *(const float4*)&wr[j*8];
      float4 v1 = *(const float4*)&wr[j*8+4];
      F4H p;
      p.h2[0][0]=(_Float16)v0.x; p.h2[0][1]=(_Float16)v0.y;
      p.h2[1][0]=(_Float16)v0.z; p.h2[1][1]=(_Float16)v0.w;
      p.h2[2][0]=(_Float16)v1.x; p.h2[2][1]=(_Float16)v1.y;
      p.h2[3][0]=(_Float16)v1.z; p.h2[3][1]=(_Float16)v1.w;
      wlds4[wave][j][ke][rloc] = p.f4;
    }
  }
  h16[(tid>>5)*40 + (tid&31)] = (_Float16)0.0f;   // h_{-1}=0 (tid covers k=0..255)
  float c = 0.0f;
  __syncthreads();

  // first pregate (one contiguous 128B block per WG; 8 ke-lanes share each float)
  float pgv;
  {
    int t0 = dir ? (S_LEN-1) : 0;
    pgv = pgb[((size_t)t0*32 + wgi)*32 + q*8 + wave*2 + uloc];
  }

  for (int s=0; s<S_LEN; s++){
    int t = dir ? (S_LEN-1-s) : s;

    // matvec: a = dot(W16[row][ke*32..+32], h16[ke*32..+32])  (fp32 acc)
    float a = 0.0f;
#pragma unroll
    for (int j=0; j<4; j++){
      F4H w; w.f4 = wlds4[wave][j][ke][rloc];
      F4H h; h.f4 = *(const float4*)&h16[ke*40 + j*8];
      a = dot2f(w.h2[0], h.h2[0], a);
      a = dot2f(w.h2[1], h.h2[1], a);
      a = dot2f(w.h2[2], h.h2[2], a);
      a = dot2f(w.h2[3], h.h2[3], a);
    }
    // butterfly over ke: all 8 lanes of the row group get the full sum
    a += __shfl_xor(a, 1);
    a += __shfl_xor(a, 2);
    a += __shfl_xor(a, 4);
    a += pgv;

    // per-lane activation (gate g=q2 uses tanh = 2*sigmoid(2x)-1)
    float xx  = (q==2) ? (a + a) : a;
    float sg  = sigmoid_f(xx);
    float act = (q==2) ? (sg + sg - 1.0f) : sg;

    // gather all 4 gates of this lane's unit (within-wave)
    int base = uloc*32 + ke;
    float iA = __shfl(act, base);
    float fA = __shfl(act, base + 8);
    float gA = __shfl(act, base + 16);
    float oA = __shfl(act, base + 24);
    c = fA*c + iA*gA;
    float hn = oA * tanh_f(c);

    if ((l & 31) == 0){           // lane (q==0,ke==0) of each unit group
      unsigned long long pack =
          ((unsigned long long)__float_as_uint(hn) << 32) | (unsigned long long)(unsigned)(s+1);
      __hip_atomic_store(&hb[(s&1)*H2 + u], pack,
                         __ATOMIC_RELAXED, __HIP_MEMORY_SCOPE_AGENT);
      hout[(size_t)t*512 + dir*H2 + u] = hn;
    }

    if (s+1 < S_LEN){
      // prefetch next pregate BEFORE the poll (HBM latency hides behind the spin)
      int tn = dir ? (S_LEN-2-s) : (s+1);
      pgv = pgb[((size_t)tn*32 + wgi)*32 + q*8 + wave*2 + uloc];

      // distributed poll: wave w covers slots [64w, 64w+64), 1 coalesced u64/lane
      {
        unsigned tag = (unsigned)(s+1);
        int k = wave*64 + l;
        unsigned long long* __restrict__ slot = &hb[(s&1)*H2 + k];
        unsigned long long vv;
        do {
          vv = __hip_atomic_load(slot, __ATOMIC_RELAXED, __HIP_MEMORY_SCOPE_AGENT);
        } while ((unsigned)vv != tag);
        h16[(k>>5)*40 + (k&31)] = (_Float16)__uint_as_float((unsigned)(vv>>32));
      }
      __syncthreads();            // single barrier per step
    }
  }
}

// ---------------------------------------------------------------- k_output
__global__ __launch_bounds__(256) void k_output(
    const float* __restrict__ hout, const float* __restrict__ outW,
    const float* __restrict__ outb, float* __restrict__ out)
{
  __shared__ float wT[128][66];
  __shared__ float hsh[32][132];
  __shared__ float lsh[32][66];
  __shared__ float msh[32][2];
  int t0 = blockIdx.x*32, tid = threadIdx.x;
  int n  = tid & 63, tg = tid >> 6;
  int sl = tid >> 3, kg = tid & 7;
  int wn = tid & 63, wk = tid >> 6;
  float acc[8];
#pragma unroll
  for (int u=0; u<8; u++) acc[u] = 0.0f;

  for (int kc=0; kc<4; kc++){
    int k0 = kc*128;
    float4 wreg[8];
#pragma unroll
    for (int e=0; e<8; e++) wreg[e] = *(const float4*)&outW[(size_t)wn*512 + k0 + wk*32 + e*4];
    float4 hreg[4];
#pragma unroll
    for (int e=0; e<4; e++) hreg[e] = *(const float4*)&hout[(size_t)(t0+sl)*512 + k0 + kg*16 + e*4];
    __syncthreads();
#pragma unroll
    for (int e=0; e<8; e++){
      int kk = wk*32 + e*4;
      wT[kk+0][wn]=wreg[e].x; wT[kk+1][wn]=wreg[e].y; wT[kk+2][wn]=wreg[e].z; wT[kk+3][wn]=wreg[e].w;
    }
#pragma unroll
    for (int e=0; e<4; e++) *(float4*)&hsh[sl][kg*16 + e*4] = hreg[e];
    __syncthreads();
#pragma unroll
    for (int kk4=0; kk4<128; kk4+=4){
      float w0 = wT[kk4+0][n], w1 = wT[kk4+1][n], w2 = wT[kk4+2][n], w3 = wT[kk4+3][n];
#pragma unroll
      for (int u=0; u<8; u++){
        float4 h4 = *(const float4*)&hsh[tg*8+u][kk4];
        acc[u] += w0*h4.x + w1*h4.y + w2*h4.z + w3*h4.w;
      }
    }
  }
  float bn = outb[n];
#pragma unroll
  for (int u=0; u<8; u++) lsh[tg*8+u][n] = acc[u] + bn;
  __syncthreads();
  if (tid < 32){
    float M = -3.4e38f;
    for (int j=0; j<NTAG; j++) M = fmaxf(M, lsh[tid][j]);
    float ssum = 0.0f;
    for (int j=0; j<NTAG; j++) ssum += expf(lsh[tid][j] - M);
    msh[tid][0] = M; msh[tid][1] = logf(ssum);
  }
  __syncthreads();
#pragma unroll
  for (int u=0; u<8; u++){
    int tt = tg*8+u;
    out[(size_t)(t0+tt)*NTAG + n] = lsh[tt][n] - msh[tt][0] - msh[tt][1];
  }
}

// ---------------------------------------------------------------- launch
extern "C" void kernel_launch(void* const* d_in, const int* in_sizes, int n_in,
                              void* d_out, int out_size, void* d_ws, size_t ws_size,
                              hipStream_t stream)
{
  (void)in_sizes; (void)n_in; (void)out_size; (void)ws_size;
  const int*   sentence = (const int*)d_in[0];
  const int*   charsets = (const int*)d_in[1];
  const int*   char_len = (const int*)d_in[2];
  const float* word_emb = (const float*)d_in[3];
  const float* char_emb = (const float*)d_in[4];
  const float* char_Wih = (const float*)d_in[5];
  const float* char_Whh = (const float*)d_in[6];
  const float* char_b   = (const float*)d_in[7];
  const float* fw_Wih   = (const float*)d_in[8];
  const float* fw_Whh   = (const float*)d_in[9];
  const float* fw_b     = (const float*)d_in[10];
  const float* bw_Wih   = (const float*)d_in[11];
  const float* bw_Whh   = (const float*)d_in[12];
  const float* bw_b     = (const float*)d_in[13];
  const float* out_W    = (const float*)d_in[14];
  const float* out_b    = (const float*)d_in[15];
  float* out = (float*)d_out;

  char* ws = (char*)d_ws;
  float* preC     = (float*)(ws);
  float* whhTc    = (float*)(ws + 262144);
  float* embeds   = (float*)(ws + 524288);
  float* pregates = (float*)(ws + 13107200);
  float* houtb    = (float*)(ws + 80216064);
  unsigned long long* hbuf = (unsigned long long*)(ws + 96993280);

  k_prep     <<<256,  512, 0, stream>>>(char_emb, char_Wih, char_Whh, char_b, preC, whhTc);
  k_char_lstm<<<512,  256, 0, stream>>>(charsets, char_len, preC, whhTc, embeds);
  k_gather   <<<1024, 256, 0, stream>>>(sentence, word_emb, embeds);
  k_pregate  <<<dim3(128,16,2), 256, 0, stream>>>(embeds, fw_Wih, fw_b, bw_Wih, bw_b, pregates);
  k_recurrent<<<64,   256, 0, stream>>>(fw_Whh, bw_Whh, pregates, hbuf, houtb);
  k_output   <<<256,  256, 0, stream>>>(houtb, out_W, out_b, out);
}